// Round 5
// baseline (155.686 us; speedup 1.0000x reference)
//
#include <hip/hip_runtime.h>
#include <cstdint>
#include <cstddef>

#define NN 4096
#define FDIM 256

typedef __attribute__((ext_vector_type(4))) float fx4;
typedef __attribute__((ext_vector_type(8))) short s8v;

__device__ inline uint16_t f2bf(float f) {
    union { float f; uint32_t u; } v; v.f = f;
    const uint32_t u = v.u;
    return (uint16_t)((u + 0x7FFFu + ((u >> 16) & 1u)) >> 16);
}

// ---------------- k_h: h = x @ W.T + b  +  adj bit-pack (overlapped) ----------------
// Outputs: gt = bf16(h) transposed [f][j] linear, a1p/a2p partials, and
// bitw = adj packed to 1 bit/entry (2 MB). The 64 MB adj read rides the idle
// memory pipe of this VALU-bound GEMM (8 int4 loads/thread/phase, consumed
// after the FMA loop so latency hides under compute).
__global__ __launch_bounds__(512, 4) void k_h(const float* __restrict__ x,
        const float* __restrict__ W, const float* __restrict__ bias,
        const float* __restrict__ att_w, const int* __restrict__ adj,
        uint16_t* __restrict__ gt, uint32_t* __restrict__ bitw,
        float* __restrict__ a1p, float* __restrict__ a2p) {
    __shared__ __align__(16) float xs[2][64 * 68];
    __shared__ __align__(16) float wt[2][64 * 68];
    const int bi = blockIdx.x, bf = blockIdx.y;
    const int t = threadIdx.x;
    const int t256 = t & 255;
    const int kh = t >> 8;                         // K-half: 0 or 1
    const int tx = t256 & 15, ty = t256 >> 4;      // f-group, i-group
    const int pr0 = (bi * 4 + bf) * 16;            // this block's 16 adj rows
    float acc[4][4] = {};
    float rx[8], rw[8];
    #pragma unroll
    for (int u = 0; u < 8; ++u) {
        const int e = t + 512 * u, r = e >> 6, c = e & 63;
        rx[u] = x[(size_t)(bi * 64 + r) * 256 + c];
        rw[u] = W[(size_t)(bf * 64 + r) * 256 + c];
    }
    for (int p = 0; p < 4; ++p) {
        float* xb = xs[p & 1];
        float* wb = wt[p & 1];
        #pragma unroll
        for (int u = 0; u < 8; ++u) {
            const int e = t + 512 * u, r = e >> 6, c = e & 63;
            const int sw = 8 * ((c & 7) ^ ((c >> 3) & 7));
            xb[c * 68 + (r ^ sw)] = rx[u];
            wb[c * 68 + (r ^ sw)] = rw[u];
        }
        __syncthreads();
        if (p < 3) {
            const int kc = (p + 1) * 64;
            #pragma unroll
            for (int u = 0; u < 8; ++u) {
                const int e = t + 512 * u, r = e >> 6, c = e & 63;
                rx[u] = x[(size_t)(bi * 64 + r) * 256 + kc + c];
                rw[u] = W[(size_t)(bf * 64 + r) * 256 + kc + c];
            }
        }
        // ---- adj pack loads for this phase (1 u32 word = 32 ints/thread) ----
        const int wi = p * 512 + t;
        const int prow = pr0 + (wi >> 7), pw = wi & 127;
        int4 pa[8];
        {
            const int* ap = adj + (size_t)prow * NN + pw * 32;
            #pragma unroll
            for (int j = 0; j < 8; ++j) pa[j] = *(const int4*)(ap + j * 4);
        }
        #pragma unroll 8
        for (int k = 0; k < 32; ++k) {
            const int kk = kh * 32 + k;
            const int sw = 8 * ((kk & 7) ^ ((kk >> 3) & 7));
            const fx4 av = *(const fx4*)(xb + kk * 68 + ((ty * 4) ^ sw));
            const fx4 bv = *(const fx4*)(wb + kk * 68 + ((tx * 4) ^ sw));
            #pragma unroll
            for (int u = 0; u < 4; ++u)
                #pragma unroll
                for (int v = 0; v < 4; ++v)
                    acc[u][v] += av[u] * bv[v];
        }
        // ---- pack + store (loads completed under the FMA loop) ----
        uint32_t bm = 0;
        #pragma unroll
        for (int j = 0; j < 8; ++j) {
            bm |= (uint32_t)(pa[j].x & 1) << (4 * j);
            bm |= (uint32_t)(pa[j].y & 1) << (4 * j + 1);
            bm |= (uint32_t)(pa[j].z & 1) << (4 * j + 2);
            bm |= (uint32_t)(pa[j].w & 1) << (4 * j + 3);
        }
        bitw[(size_t)prow * 128 + pw] = bm;
    }
    __syncthreads();
    float* cbuf = xs[0];
    if (kh == 1) {
        #pragma unroll
        for (int u = 0; u < 4; ++u)
            *(fx4*)(cbuf + t256 * 16 + u * 4) = *(const fx4*)(&acc[u][0]);
    }
    __syncthreads();
    if (kh == 0) {
        float* tileT = wt[0];     // dead after compute: [f_local][j_local] pad 68
        #pragma unroll
        for (int u = 0; u < 4; ++u) {
            const fx4 o = *(const fx4*)(cbuf + t256 * 16 + u * 4);
            #pragma unroll
            for (int v = 0; v < 4; ++v) acc[u][v] += o[v];
        }
        const fx4 bv = *(const fx4*)(bias + bf * 64 + tx * 4);
        const fx4 w1v = *(const fx4*)(att_w + bf * 64 + tx * 4);
        const fx4 w2v = *(const fx4*)(att_w + 256 + bf * 64 + tx * 4);
        #pragma unroll
        for (int u = 0; u < 4; ++u) {
            const int i = bi * 64 + ty * 4 + u;
            fx4 r;
            float s1 = 0.f, s2 = 0.f;
            #pragma unroll
            for (int v = 0; v < 4; ++v) {
                r[v] = acc[u][v] + bv[v];
                s1 += r[v] * w1v[v];
                s2 += r[v] * w2v[v];
            }
            #pragma unroll
            for (int v = 0; v < 4; ++v)
                tileT[(tx * 4 + v) * 68 + ty * 4 + u] = r[v];
            #pragma unroll
            for (int d = 8; d > 0; d >>= 1) {
                s1 += __shfl_down(s1, d, 16);
                s2 += __shfl_down(s2, d, 16);
            }
            if (tx == 0) {
                a1p[bf * NN + i] = s1;
                a2p[bf * NN + i] = s2;
            }
        }
    }
    __syncthreads();
    {   // gt store: all 512 threads, 64 f-rows x 8 col-groups of 8 (linear)
        const float* tileT = wt[0];
        const int fl = t >> 3, cb = t & 7;
        s8v v;
        #pragma unroll
        for (int lo = 0; lo < 8; ++lo)
            v[lo] = (short)f2bf(tileT[fl * 68 + cb * 8 + lo]);
        *(s8v*)(gt + (size_t)(bf * 64 + fl) * NN + bi * 64 + cb * 8) = v;
    }
}

// ---- k_prep: reduce a-partials, max/exp -> E1,E2, Sg=0, edge scan -> wbf ----
__global__ __launch_bounds__(1024) void k_prep(const float* __restrict__ a1p,
        const float* __restrict__ a2p, const int* __restrict__ adj,
        float* __restrict__ E1, float* __restrict__ E2,
        uint16_t* __restrict__ wbf, float* __restrict__ Sg) {
    __shared__ float E1s[NN];
    __shared__ float E2s[NN];
    __shared__ float wraw_s[NN];
    __shared__ float red1[16], red2[16];
    __shared__ int wtot[16];
    __shared__ int base_s;
    const int t = threadIdx.x, lane = t & 63, wv = t >> 6;
    fx4 v1 = {0.f, 0.f, 0.f, 0.f}, v2 = {0.f, 0.f, 0.f, 0.f};
    #pragma unroll
    for (int bf = 0; bf < 4; ++bf) {
        v1 += *(const fx4*)(a1p + bf * NN + t * 4);
        v2 += *(const fx4*)(a2p + bf * NN + t * 4);
    }
    float m1 = fmaxf(fmaxf(v1[0], v1[1]), fmaxf(v1[2], v1[3]));
    float m2 = fmaxf(fmaxf(v2[0], v2[1]), fmaxf(v2[2], v2[3]));
    #pragma unroll
    for (int d = 32; d > 0; d >>= 1) {
        m1 = fmaxf(m1, __shfl_down(m1, d));
        m2 = fmaxf(m2, __shfl_down(m2, d));
    }
    if (lane == 0) { red1[wv] = m1; red2[wv] = m2; }
    __syncthreads();
    if (t == 0) {
        float mm1 = -1e30f, mm2 = -1e30f;
        for (int k = 0; k < 16; ++k) {
            mm1 = fmaxf(mm1, red1[k]);
            mm2 = fmaxf(mm2, red2[k]);
        }
        red1[0] = mm1; red2[0] = mm2;
        *Sg = 0.f;
        base_s = 0;
    }
    __syncthreads();
    const float M1 = red1[0], M2 = red2[0];
    fx4 e1v, e2v, z4 = {0.f, 0.f, 0.f, 0.f};
    #pragma unroll
    for (int j = 0; j < 4; ++j) {
        e1v[j] = expf(v1[j] - M1);
        e2v[j] = expf(v2[j] - M2);
    }
    *(fx4*)(E1s + t * 4) = e1v;
    *(fx4*)(E2s + t * 4) = e2v;
    *(fx4*)(E1 + t * 4) = e1v;
    *(fx4*)(E2 + t * 4) = e2v;
    *(fx4*)(wraw_s + t * 4) = z4;
    __syncthreads();
    for (int row = 0; row < NN; ++row) {
        const int base = base_s;           // uniform
        if (base >= NN) break;             // uniform break
        const int4 a = ((const int4*)(adj + (size_t)row * NN))[t];
        const int vj[4] = {a.x, a.y, a.z, a.w};
        int cnt = 0;
        #pragma unroll
        for (int j = 0; j < 4; ++j) cnt += (vj[j] == 1);
        int inc = cnt;
        #pragma unroll
        for (int d = 1; d < 64; d <<= 1) {
            const int y = __shfl_up(inc, d);
            if (lane >= d) inc += y;
        }
        if (lane == 63) wtot[wv] = inc;
        __syncthreads();                   // B1
        int wbase = 0, total = 0;
        #pragma unroll
        for (int w = 0; w < 16; ++w) {
            const int xw = wtot[w];
            total += xw;
            wbase += (w < wv) ? xw : 0;
        }
        if (t == 0) base_s = base + total;
        int r = base + wbase + inc - cnt;
        if (cnt && r < NN) {
            const float e1 = E1s[row];
            #pragma unroll
            for (int j = 0; j < 4; ++j) {
                if (vj[j] == 1) {
                    if (r < NN) wraw_s[r] = e1 * E2s[t * 4 + j];
                    ++r;
                }
            }
        }
        __syncthreads();                   // B2
    }
    __syncthreads();
    {   // wbf = bf16(wraw) table for k_fused's A-operand staging
        const fx4 wv4 = *(const fx4*)(wraw_s + t * 4);
        uint2 o;
        o.x = (uint32_t)f2bf(wv4[0]) | ((uint32_t)f2bf(wv4[1]) << 16);
        o.y = (uint32_t)f2bf(wv4[2]) | ((uint32_t)f2bf(wv4[3]) << 16);
        *(uint2*)(wbf + t * 4) = o;
    }
}

// -------- k_fused: part = (bits * wbf) @ gt^T (bf16 MFMA, split-K) + exact S ----
// R5: adj HBM stream replaced by the 2 MB L2-resident bitmask. Per thread/step:
// 1 u32 bit-word + 32 B wbf + 64 B E2 (all L2-hot, shared across ib-blocks).
// B-operand in regs (wave-private gt rows), As double-buffered, 1 barrier/step.
__global__ __launch_bounds__(256, 2) void k_fused(const uint32_t* __restrict__ bitw,
        const uint16_t* __restrict__ gt, const float* __restrict__ E1,
        const float* __restrict__ E2, const uint16_t* __restrict__ wbf,
        uint16_t* __restrict__ part, float* __restrict__ Sg, int krange) {
    __shared__ __align__(16) uint16_t As[2][64 * 72];
    __shared__ float sgred[4];
    const int ib = blockIdx.x, ks = blockIdx.y;
    const int t = threadIdx.x;
    const int wv = t >> 6, lane = t & 63;
    const int q = lane >> 4, m16 = lane & 15;
    const int i0 = ib * 64, k0 = ks * krange;
    const int ksteps = krange >> 6;                    // even (8/16/32/64)
    const int srow = t & 63, scg = t >> 6;             // stage: row, 16-col group
    const int sh = (scg & 1) * 16;
    fx4 acc[4][4];
    #pragma unroll
    for (int a = 0; a < 4; ++a)
        #pragma unroll
        for (int b2 = 0; b2 < 4; ++b2) acc[a][b2] = (fx4){0.f, 0.f, 0.f, 0.f};
    float sS = 0.f;
    const float e1row = E1[i0 + srow];
    const uint32_t* brow = bitw + (size_t)(i0 + srow) * 128 + (k0 >> 5) + (scg >> 1);
    // per-lane B row pointers (q*8 folded in): B[k][col] = gt[col][k]
    const uint16_t* rowp[4];
    #pragma unroll
    for (int ft = 0; ft < 4; ++ft)
        rowp[ft] = gt + (size_t)(wv * 64 + ft * 16 + m16) * NN + q * 8;

    // prologue: step-0 operands
    uint32_t bitsC = brow[0];
    uint4 wpC0 = *(const uint4*)(wbf + k0 + scg * 16);
    uint4 wpC1 = *(const uint4*)(wbf + k0 + scg * 16 + 8);
    s8v B0[4][2], B1[4][2];
    #pragma unroll
    for (int ft = 0; ft < 4; ++ft) {
        B0[ft][0] = *(const s8v*)(rowp[ft] + k0);
        B0[ft][1] = *(const s8v*)(rowp[ft] + k0 + 32);
    }

    auto step = [&](s8v (&Bc)[4][2], s8v (&Bn)[4][2], int stp) {
        const int cur = stp & 1;
        const int kk = k0 + stp * 64;
        // ---- stage As[cur]: bit gate x wbf, + exact S partial ----
        fx4 e2v[4];
        #pragma unroll
        for (int j = 0; j < 4; ++j)
            e2v[j] = *(const fx4*)(E2 + kk + scg * 16 + j * 4);
        const uint32_t bits = bitsC >> sh;
        uint32_t wpa[8];
        wpa[0] = wpC0.x; wpa[1] = wpC0.y; wpa[2] = wpC0.z; wpa[3] = wpC0.w;
        wpa[4] = wpC1.x; wpa[5] = wpC1.y; wpa[6] = wpC1.z; wpa[7] = wpC1.w;
        float s16 = 0.f;
        uint32_t ob[8];
        #pragma unroll
        for (int pp = 0; pp < 8; ++pp) {
            const uint32_t b0 = (bits >> (2 * pp)) & 1u;
            const uint32_t b1 = (bits >> (2 * pp + 1)) & 1u;
            ob[pp] = wpa[pp] & ((b0 ? 0xFFFFu : 0u) | (b1 ? 0xFFFF0000u : 0u));
            s16 += (b0 ? e2v[pp >> 1][(pp & 1) * 2] : 0.f) +
                   (b1 ? e2v[pp >> 1][(pp & 1) * 2 + 1] : 0.f);
        }
        sS += e1row * s16;
        uint16_t* dstAs = &As[cur][srow * 72 + scg * 16];
        *(uint2*)(dstAs + 0)  = make_uint2(ob[0], ob[1]);
        *(uint2*)(dstAs + 4)  = make_uint2(ob[2], ob[3]);
        *(uint2*)(dstAs + 8)  = make_uint2(ob[4], ob[5]);
        *(uint2*)(dstAs + 12) = make_uint2(ob[6], ob[7]);
        __syncthreads();   // As[cur] visible; other buffer free to stage next
        // ---- prefetch next step (all L2-resident): hides under MFMA ----
        if (stp + 1 < ksteps) {
            bitsC = brow[(stp + 1) * 2];
            wpC0 = *(const uint4*)(wbf + kk + 64 + scg * 16);
            wpC1 = *(const uint4*)(wbf + kk + 64 + scg * 16 + 8);
            #pragma unroll
            for (int ft = 0; ft < 4; ++ft) {
                Bn[ft][0] = *(const s8v*)(rowp[ft] + kk + 64);
                Bn[ft][1] = *(const s8v*)(rowp[ft] + kk + 64 + 32);
            }
        }
        // ---- MFMA: A from LDS, B from regs ----
        s8v afr[4][2];
        #pragma unroll
        for (int it = 0; it < 4; ++it)
            #pragma unroll
            for (int khh = 0; khh < 2; ++khh)
                afr[it][khh] = *(const s8v*)(&As[cur][(it * 16 + m16) * 72 +
                                                      khh * 32 + q * 8]);
        #pragma unroll
        for (int ft = 0; ft < 4; ++ft)
            #pragma unroll
            for (int khh = 0; khh < 2; ++khh)
                #pragma unroll
                for (int it = 0; it < 4; ++it)
                    acc[it][ft] = __builtin_amdgcn_mfma_f32_16x16x32_bf16(
                        afr[it][khh], Bc[ft][khh], acc[it][ft], 0, 0, 0);
    };

    for (int stp = 0; stp < ksteps; stp += 2) {
        step(B0, B1, stp);
        step(B1, B0, stp + 1);
    }

    #pragma unroll
    for (int d = 32; d > 0; d >>= 1) sS += __shfl_down(sS, d);
    if (lane == 0) sgred[wv] = sS;
    __syncthreads();
    if (t == 0)
        atomicAdd(Sg, sgred[0] + sgred[1] + sgred[2] + sgred[3]);
    // bf16 partials; C/D layout: col=lane&15, row=(lane>>4)*4+reg
    uint16_t* dst = part + (size_t)ks * NN * FDIM;
    #pragma unroll
    for (int it = 0; it < 4; ++it) {
        #pragma unroll
        for (int ft = 0; ft < 4; ++ft) {
            const int f = wv * 64 + ft * 16 + m16;
            #pragma unroll
            for (int r = 0; r < 4; ++r) {
                const int i = i0 + it * 16 + q * 4 + r;
                dst[(size_t)i * FDIM + f] = f2bf(acc[it][ft][r]);
            }
        }
    }
}

// -------- k_out: out = relu(sum_k part_k) / S (bf16 partials, 8 f/thread) --------
__global__ __launch_bounds__(256) void k_out(const uint16_t* __restrict__ part,
        const float* __restrict__ Sg, float* __restrict__ out, int nsplit) {
    const size_t idx = ((size_t)blockIdx.x * 256 + threadIdx.x) * 8;
    const float inv = 1.0f / (*Sg);
    float s[8] = {};
    for (int k = 0; k < nsplit; ++k) {
        const s8v v = *(const s8v*)(part + (size_t)k * NN * FDIM + idx);
        #pragma unroll
        for (int j = 0; j < 8; ++j) {
            union { uint32_t u; float f; } cv;
            cv.u = ((uint32_t)(uint16_t)v[j]) << 16;
            s[j] += cv.f;
        }
    }
    fx4 r0, r1;
    #pragma unroll
    for (int j = 0; j < 4; ++j) {
        r0[j] = fmaxf(s[j], 0.f) * inv;
        r1[j] = fmaxf(s[4 + j], 0.f) * inv;
    }
    *(fx4*)(out + idx) = r0;
    *(fx4*)(out + idx + 4) = r1;
}

extern "C" void kernel_launch(void* const* d_in, const int* in_sizes, int n_in,
                              void* d_out, int out_size, void* d_ws, size_t ws_size,
                              hipStream_t stream) {
    const float* x     = (const float*)d_in[0];
    const int*   adj   = (const int*)d_in[1];
    const float* W     = (const float*)d_in[2];
    const float* bias  = (const float*)d_in[3];
    const float* att_w = (const float*)d_in[4];
    // att_b (d_in[5]) cancels exactly in the softmax — unused.
    float* out = (float*)d_out;
    char* ws = (char*)d_ws;
    uint16_t* gt   = (uint16_t*)(ws + 0);            // 2 MB: bf16(h) transposed
    uint32_t* bitw = (uint32_t*)(ws + 2097152);      // 2 MB: adj bitmask
    float*    a1p  = (float*)(ws + 4194304);         // 64 KB (4 x 4096)
    float*    a2p  = (float*)(ws + 4259840);         // 64 KB
    float*    E1   = (float*)(ws + 4325376);         // 16 KB
    float*    E2   = (float*)(ws + 4341760);         // 16 KB
    uint16_t* wbf  = (uint16_t*)(ws + 4358144);      // 8 KB: bf16(wraw)
    float*    Sg   = (float*)(ws + 4366336);         // 256 B
    uint16_t* part = (uint16_t*)(ws + 4366592);      // splitk x 2 MB (bf16)
    (void)in_sizes; (void)n_in; (void)out_size;

    const size_t avail = (ws_size > 4366592) ? (ws_size - 4366592) : 0;
    int splitk = 1;
    while (splitk < 8 &&
           (size_t)(splitk * 2) * NN * FDIM * sizeof(uint16_t) <= avail)
        splitk <<= 1;
    const int krange = NN / splitk;

    k_h    <<<dim3(64, 4), 512, 0, stream>>>(x, W, bias, att_w, adj, gt, bitw, a1p, a2p);
    k_prep <<<dim3(1), 1024, 0, stream>>>(a1p, a2p, adj, E1, E2, wbf, Sg);
    k_fused<<<dim3(64, splitk), 256, 0, stream>>>(bitw, gt, E1, E2, wbf, part, Sg, krange);
    k_out  <<<dim3(512), 256, 0, stream>>>(part, Sg, out, splitk);
}

// Round 6
// 154.243 us; speedup vs baseline: 1.0094x; 1.0094x over previous
//
#include <hip/hip_runtime.h>
#include <cstdint>
#include <cstddef>

#define NN 4096
#define FDIM 256
#define SPLITK 8
#define KRANGE 512          // NN / SPLITK
#define KSTEPS 8            // KRANGE / 64

typedef __attribute__((ext_vector_type(4))) float fx4;
typedef __attribute__((ext_vector_type(8))) short s8v;

__device__ inline uint16_t f2bf(float f) {
    union { float f; uint32_t u; } v; v.f = f;
    const uint32_t u = v.u;
    return (uint16_t)((u + 0x7FFFu + ((u >> 16) & 1u)) >> 16);
}

// ---------------- k_h: h = x @ W.T + b (kept in regs/LDS only) ----------------
// Outputs: gt = bf16(h) transposed [f][j] cb-swizzled (MFMA B-operand layout),
// a1p/a2p = per-f-chunk partials of h@att_w1 / h@att_w2, Sg = 0. h never hits HBM.
// R3-measured-best version, unchanged except the Sg zero.
__global__ __launch_bounds__(512, 4) void k_h(const float* __restrict__ x,
        const float* __restrict__ W, const float* __restrict__ bias,
        const float* __restrict__ att_w, uint16_t* __restrict__ gt,
        float* __restrict__ a1p, float* __restrict__ a2p, float* __restrict__ Sg) {
    __shared__ __align__(16) float xs[2][64 * 68];
    __shared__ __align__(16) float wt[2][64 * 68];
    const int bi = blockIdx.x, bf = blockIdx.y;
    const int t = threadIdx.x;
    const int t256 = t & 255;
    const int kh = t >> 8;                         // K-half: 0 or 1
    const int tx = t256 & 15, ty = t256 >> 4;      // f-group, i-group
    if (bi == 0 && bf == 0 && t == 0) *Sg = 0.f;   // k_fused atomics start clean
    float acc[4][4] = {};
    float rx[8], rw[8];
    #pragma unroll
    for (int u = 0; u < 8; ++u) {
        const int e = t + 512 * u, r = e >> 6, c = e & 63;
        rx[u] = x[(size_t)(bi * 64 + r) * 256 + c];
        rw[u] = W[(size_t)(bf * 64 + r) * 256 + c];
    }
    for (int p = 0; p < 4; ++p) {
        float* xb = xs[p & 1];
        float* wb = wt[p & 1];
        #pragma unroll
        for (int u = 0; u < 8; ++u) {
            const int e = t + 512 * u, r = e >> 6, c = e & 63;
            const int sw = 8 * ((c & 7) ^ ((c >> 3) & 7));
            xb[c * 68 + (r ^ sw)] = rx[u];
            wb[c * 68 + (r ^ sw)] = rw[u];
        }
        __syncthreads();
        if (p < 3) {
            const int kc = (p + 1) * 64;
            #pragma unroll
            for (int u = 0; u < 8; ++u) {
                const int e = t + 512 * u, r = e >> 6, c = e & 63;
                rx[u] = x[(size_t)(bi * 64 + r) * 256 + kc + c];
                rw[u] = W[(size_t)(bf * 64 + r) * 256 + kc + c];
            }
        }
        #pragma unroll 8
        for (int k = 0; k < 32; ++k) {
            const int kk = kh * 32 + k;
            const int sw = 8 * ((kk & 7) ^ ((kk >> 3) & 7));
            const fx4 av = *(const fx4*)(xb + kk * 68 + ((ty * 4) ^ sw));
            const fx4 bv = *(const fx4*)(wb + kk * 68 + ((tx * 4) ^ sw));
            #pragma unroll
            for (int u = 0; u < 4; ++u)
                #pragma unroll
                for (int v = 0; v < 4; ++v)
                    acc[u][v] += av[u] * bv[v];
        }
    }
    __syncthreads();
    float* cbuf = xs[0];
    if (kh == 1) {
        #pragma unroll
        for (int u = 0; u < 4; ++u)
            *(fx4*)(cbuf + t256 * 16 + u * 4) = *(const fx4*)(&acc[u][0]);
    }
    __syncthreads();
    if (kh == 0) {
        float* tileT = wt[0];     // dead after compute: [f_local][j_local] pad 68
        #pragma unroll
        for (int u = 0; u < 4; ++u) {
            const fx4 o = *(const fx4*)(cbuf + t256 * 16 + u * 4);
            #pragma unroll
            for (int v = 0; v < 4; ++v) acc[u][v] += o[v];
        }
        const fx4 bv = *(const fx4*)(bias + bf * 64 + tx * 4);
        const fx4 w1v = *(const fx4*)(att_w + bf * 64 + tx * 4);
        const fx4 w2v = *(const fx4*)(att_w + 256 + bf * 64 + tx * 4);
        #pragma unroll
        for (int u = 0; u < 4; ++u) {
            const int i = bi * 64 + ty * 4 + u;
            fx4 r;
            float s1 = 0.f, s2 = 0.f;
            #pragma unroll
            for (int v = 0; v < 4; ++v) {
                r[v] = acc[u][v] + bv[v];
                s1 += r[v] * w1v[v];
                s2 += r[v] * w2v[v];
            }
            #pragma unroll
            for (int v = 0; v < 4; ++v)
                tileT[(tx * 4 + v) * 68 + ty * 4 + u] = r[v];
            #pragma unroll
            for (int d = 8; d > 0; d >>= 1) {
                s1 += __shfl_down(s1, d, 16);
                s2 += __shfl_down(s2, d, 16);
            }
            if (tx == 0) {
                a1p[bf * NN + i] = s1;
                a2p[bf * NN + i] = s2;
            }
        }
    }
    __syncthreads();
    {   // gt store: all 512 threads, 64 f-rows x 8 cb-groups of 8 (swizzled)
        const float* tileT = wt[0];
        const int fl = t >> 3, cb = t & 7;
        const int pcb = cb ^ (fl & 7);
        s8v v;
        #pragma unroll
        for (int lo = 0; lo < 8; ++lo)
            v[lo] = (short)f2bf(tileT[fl * 68 + cb * 8 + lo]);
        *(s8v*)(gt + (size_t)(bf * 64 + fl) * NN + bi * 64 + pcb * 8) = v;
    }
}

// -------- k_fused: part = (adj * bf16(wraw)) @ gt^T (bf16 MFMA, split-K) + S ----
// R6: k_prep is GONE. Each block replicates the softmax prep in a parallel
// prologue from L2-hot data (a1p/a2p 128 KB, adj rows 0..~2): exact M1/M2,
// f32 E2 window, e1 regs, and the first-4096-edge scan restricted to this
// block's K-window -> bf16 wraw in LDS. Reduction orders replicate k_prep
// bitwise. Main loop = R3-measured-best structure verbatim (Gs DMA + As stage
// + adj one-step prefetch), with wraw/E2 reads now from LDS.
__global__ __launch_bounds__(256, 3) void k_fused(const int* __restrict__ adj,
        const uint16_t* __restrict__ gt, const float* __restrict__ a1p,
        const float* __restrict__ a2p, uint16_t* __restrict__ part,
        float* __restrict__ Sg) {
    __shared__ __align__(16) uint16_t As[64 * 72];     // padded (explicit writes)
    __shared__ __align__(16) uint16_t Gs[256 * 64];    // linear (DMA target)
    __shared__ __align__(16) float E2w[KRANGE];        // f32 E2, this K-window
    __shared__ __align__(16) uint16_t wbf[KRANGE];     // bf16 wraw, this K-window
    __shared__ float mred[8];
    __shared__ int wtot[4];
    __shared__ float sgred[4];
    const int ib = blockIdx.x, ks = blockIdx.y;
    const int t = threadIdx.x;
    const int wv = t >> 6, lane = t & 63;
    const int q = lane >> 4, m16 = lane & 15;
    const int i0 = ib * 64, k0 = ks * KRANGE;
    const int ar = t >> 4, ac4 = (t & 15) * 4;         // adj/As staging mapping
    const int fr = lane >> 3, cb = lane & 7;           // Gs DMA lane mapping

    // ================= prologue: replicate k_prep for this block ==============
    // M1/M2: global maxes of a1/a2 (chunk-sum order = k_prep's, max exact)
    {
        float lm1 = -1e30f, lm2 = -1e30f;
        #pragma unroll
        for (int j = 0; j < 4; ++j) {
            const int idx = t * 16 + j * 4;
            fx4 s1 = *(const fx4*)(a1p + idx);
            fx4 s2 = *(const fx4*)(a2p + idx);
            #pragma unroll
            for (int c = 1; c < 4; ++c) {
                s1 += *(const fx4*)(a1p + c * NN + idx);
                s2 += *(const fx4*)(a2p + c * NN + idx);
            }
            lm1 = fmaxf(lm1, fmaxf(fmaxf(s1[0], s1[1]), fmaxf(s1[2], s1[3])));
            lm2 = fmaxf(lm2, fmaxf(fmaxf(s2[0], s2[1]), fmaxf(s2[2], s2[3])));
        }
        #pragma unroll
        for (int d = 32; d > 0; d >>= 1) {
            lm1 = fmaxf(lm1, __shfl_down(lm1, d));
            lm2 = fmaxf(lm2, __shfl_down(lm2, d));
        }
        if (lane == 0) { mred[wv] = lm1; mred[4 + wv] = lm2; }
    }
    __syncthreads();
    const float M1 = fmaxf(fmaxf(mred[0], mred[1]), fmaxf(mred[2], mred[3]));
    const float M2 = fmaxf(fmaxf(mred[4], mred[5]), fmaxf(mred[6], mred[7]));
    // E2 window (f32, exact) + e1 regs for S rows + zero wbf
    #pragma unroll
    for (int j = 0; j < 2; ++j) {
        const int c = k0 + t * 2 + j;
        float a2s = a2p[c];
        a2s += a2p[NN + c]; a2s += a2p[2 * NN + c]; a2s += a2p[3 * NN + c];
        E2w[t * 2 + j] = expf(a2s - M2);
        wbf[t * 2 + j] = 0;
    }
    float e1r[4];
    #pragma unroll
    for (int p = 0; p < 4; ++p) {
        const int i = i0 + p * 16 + ar;
        float a1s = a1p[i];
        a1s += a1p[NN + i]; a1s += a1p[2 * NN + i]; a1s += a1p[3 * NN + i];
        e1r[p] = expf(a1s - M1);
    }
    __syncthreads();
    // edge scan: global rank r over row-major edges; fill wbf for r in window
    {
        const int kend = k0 + KRANGE;
        int base = 0;
        for (int row = 0; row < NN && base < kend; ++row) {
            const int4* ap = (const int4*)(adj + (size_t)row * NN) + t * 4;
            const int4 a0 = ap[0], a1v = ap[1], a2v = ap[2], a3v = ap[3];
            const int va[16] = {a0.x, a0.y, a0.z, a0.w, a1v.x, a1v.y, a1v.z, a1v.w,
                                a2v.x, a2v.y, a2v.z, a2v.w, a3v.x, a3v.y, a3v.z, a3v.w};
            int cnt = 0;
            #pragma unroll
            for (int j = 0; j < 16; ++j) cnt += (va[j] == 1);
            int inc = cnt;
            #pragma unroll
            for (int d = 1; d < 64; d <<= 1) {
                const int y = __shfl_up(inc, d);
                if (lane >= d) inc += y;
            }
            if (lane == 63) wtot[wv] = inc;
            __syncthreads();
            int wbase = 0, total = 0;
            #pragma unroll
            for (int w = 0; w < 4; ++w) {
                const int xw = wtot[w];
                total += xw;
                wbase += (w < wv) ? xw : 0;
            }
            int r = base + wbase + inc - cnt;
            if (cnt && r < kend && r + cnt > k0) {
                float a1s = a1p[row];
                a1s += a1p[NN + row]; a1s += a1p[2 * NN + row]; a1s += a1p[3 * NN + row];
                const float e1row = expf(a1s - M1);
                #pragma unroll
                for (int j = 0; j < 16; ++j) {
                    if (va[j] == 1) {
                        if (r >= k0 && r < kend) {
                            const int col = t * 16 + j;
                            float a2s = a2p[col];
                            a2s += a2p[NN + col]; a2s += a2p[2 * NN + col];
                            a2s += a2p[3 * NN + col];
                            wbf[r - k0] = f2bf(e1row * expf(a2s - M2));
                        }
                        ++r;
                    }
                }
            }
            base += total;
            __syncthreads();
        }
    }
    __syncthreads();   // wbf/E2w ready for all

    // ================= main loop: R3 structure =================
    fx4 acc[4][4];
    #pragma unroll
    for (int a = 0; a < 4; ++a)
        #pragma unroll
        for (int b2 = 0; b2 < 4; ++b2) acc[a][b2] = (fx4){0.f, 0.f, 0.f, 0.f};
    float sS = 0.f;
    int4 ra[4];
    #pragma unroll
    for (int p = 0; p < 4; ++p)
        ra[p] = *(const int4*)(adj + (size_t)(i0 + p * 16 + ar) * NN + k0 + ac4);

    for (int stp = 0; stp < KSTEPS; ++stp) {
        const int kk = k0 + stp * 64;
        // ---- As: adj gate x bf16(wraw) + exact S partial (VALU) ----
        const uint2 ww = *(const uint2*)(&wbf[stp * 64 + ac4]);
        const fx4 re2 = *(const fx4*)(&E2w[stp * 64 + ac4]);
        #pragma unroll
        for (int p = 0; p < 4; ++p) {
            uint2 wo;
            wo.x = ww.x & ((ra[p].x == 1 ? 0xFFFFu : 0u) |
                           (ra[p].y == 1 ? 0xFFFF0000u : 0u));
            wo.y = ww.y & ((ra[p].z == 1 ? 0xFFFFu : 0u) |
                           (ra[p].w == 1 ? 0xFFFF0000u : 0u));
            *(uint2*)(&As[(p * 16 + ar) * 72 + ac4]) = wo;
            sS += e1r[p] * ((ra[p].x == 1 ? re2[0] : 0.f) +
                            (ra[p].y == 1 ? re2[1] : 0.f) +
                            (ra[p].z == 1 ? re2[2] : 0.f) +
                            (ra[p].w == 1 ? re2[3] : 0.f));
        }
        // ---- Gs: DMA 1 KB (8 f-rows) per instr, 8 instrs/wave ----
        #pragma unroll
        for (int p = 0; p < 8; ++p) {
            const int f0 = wv * 64 + p * 8;
            const uint16_t* gp = gt + (size_t)(f0 + fr) * NN + kk + cb * 8;
            __builtin_amdgcn_global_load_lds(
                (const __attribute__((address_space(1))) uint32_t*)gp,
                (__attribute__((address_space(3))) uint32_t*)(Gs + f0 * 64),
                16, 0, 0);
        }
        __syncthreads();   // drains DMA (vmcnt0) + As LDS writes
        // ---- prefetch next step's adj (drains next barrier) ----
        if (stp + 1 < KSTEPS) {
            #pragma unroll
            for (int p = 0; p < 4; ++p)
                ra[p] = *(const int4*)(adj + (size_t)(i0 + p * 16 + ar) * NN +
                                       kk + 64 + ac4);
        }
        s8v afr[4][2];
        #pragma unroll
        for (int it = 0; it < 4; ++it)
            #pragma unroll
            for (int khh = 0; khh < 2; ++khh)
                afr[it][khh] = *(const s8v*)(As + (it * 16 + m16) * 72 + khh * 32 + q * 8);
        #pragma unroll
        for (int ft = 0; ft < 4; ++ft) {
            #pragma unroll
            for (int khh = 0; khh < 2; ++khh) {
                const int row = wv * 64 + ft * 16 + m16;
                const int pcb = ((khh << 2) | q) ^ (m16 & 7);   // un-swizzle
                const s8v bfr = *(const s8v*)(Gs + row * 64 + pcb * 8);
                #pragma unroll
                for (int it = 0; it < 4; ++it)
                    acc[it][ft] = __builtin_amdgcn_mfma_f32_16x16x32_bf16(
                        afr[it][khh], bfr, acc[it][ft], 0, 0, 0);
            }
        }
        __syncthreads();   // As/Gs reusable
    }
    #pragma unroll
    for (int d = 32; d > 0; d >>= 1) sS += __shfl_down(sS, d);
    if (lane == 0) sgred[wv] = sS;
    __syncthreads();
    if (t == 0)
        atomicAdd(Sg, sgred[0] + sgred[1] + sgred[2] + sgred[3]);
    // bf16 partials; C/D layout: col=lane&15, row=(lane>>4)*4+reg
    uint16_t* dst = part + (size_t)ks * NN * FDIM;
    #pragma unroll
    for (int it = 0; it < 4; ++it) {
        #pragma unroll
        for (int ft = 0; ft < 4; ++ft) {
            const int f = wv * 64 + ft * 16 + m16;
            #pragma unroll
            for (int r = 0; r < 4; ++r) {
                const int i = i0 + it * 16 + q * 4 + r;
                dst[(size_t)i * FDIM + f] = f2bf(acc[it][ft][r]);
            }
        }
    }
}

// -------- k_out: out = relu(sum_k part_k) / S (bf16 partials, 8 f/thread) --------
__global__ __launch_bounds__(256) void k_out(const uint16_t* __restrict__ part,
        const float* __restrict__ Sg, float* __restrict__ out) {
    const size_t idx = ((size_t)blockIdx.x * 256 + threadIdx.x) * 8;
    const float inv = 1.0f / (*Sg);
    float s[8] = {};
    for (int k = 0; k < SPLITK; ++k) {
        const s8v v = *(const s8v*)(part + (size_t)k * NN * FDIM + idx);
        #pragma unroll
        for (int j = 0; j < 8; ++j) {
            union { uint32_t u; float f; } cv;
            cv.u = ((uint32_t)(uint16_t)v[j]) << 16;
            s[j] += cv.f;
        }
    }
    fx4 r0, r1;
    #pragma unroll
    for (int j = 0; j < 4; ++j) {
        r0[j] = fmaxf(s[j], 0.f) * inv;
        r1[j] = fmaxf(s[4 + j], 0.f) * inv;
    }
    *(fx4*)(out + idx) = r0;
    *(fx4*)(out + idx + 4) = r1;
}

extern "C" void kernel_launch(void* const* d_in, const int* in_sizes, int n_in,
                              void* d_out, int out_size, void* d_ws, size_t ws_size,
                              hipStream_t stream) {
    const float* x     = (const float*)d_in[0];
    const int*   adj   = (const int*)d_in[1];
    const float* W     = (const float*)d_in[2];
    const float* bias  = (const float*)d_in[3];
    const float* att_w = (const float*)d_in[4];
    // att_b (d_in[5]) cancels exactly in the softmax — unused.
    float* out = (float*)d_out;
    char* ws = (char*)d_ws;
    uint16_t* gt   = (uint16_t*)(ws + 0);            // 2 MB: bf16(h) transposed
    float*    a1p  = (float*)(ws + 2097152);         // 64 KB (4 x 4096)
    float*    a2p  = (float*)(ws + 2162688);         // 64 KB
    float*    Sg   = (float*)(ws + 2228224);         // 256 B
    uint16_t* part = (uint16_t*)(ws + 2228480);      // 8 x 2 MB (bf16)
    (void)in_sizes; (void)n_in; (void)out_size; (void)ws_size;

    k_h    <<<dim3(64, 4), 512, 0, stream>>>(x, W, bias, att_w, gt, a1p, a2p, Sg);
    k_fused<<<dim3(64, SPLITK), 256, 0, stream>>>(adj, gt, a1p, a2p, part, Sg);
    k_out  <<<dim3(512), 256, 0, stream>>>(part, Sg, out);
}